// Round 5
// baseline (5106.538 us; speedup 1.0000x reference)
//
#include <hip/hip_runtime.h>
#include <hip/hip_bf16.h>
#include <stdint.h>

typedef unsigned long long ull;

#define BATCH   16384
#define IN_DIM  784
#define INTER   1024
#define CODE    2048
#define NSTRIPE 32
#define SDIM    64
#define KNEUR   64
#define KSTR    4

__device__ __forceinline__ float bf2f(unsigned short u) {
  return __uint_as_float(((unsigned)u) << 16);
}

// ---------------------------------------------------------------------------
// Input dtype detector (insurance): fp32 words have random low-16 bits
// (~10% bf16-plausible exponents), packed-bf16 words ~100%. flag=1 => bf16.
// ---------------------------------------------------------------------------
__global__ void detect_dtype(const unsigned* __restrict__ w1raw, int* __restrict__ flag) {
  __shared__ unsigned cnt;
  if (threadIdx.x == 0) cnt = 0u;
  __syncthreads();
  unsigned c = 0;
  for (int i = threadIdx.x; i < 512; i += 256) {
    unsigned e = (w1raw[i] >> 7) & 0xFFu;
    if (e >= 100u && e <= 126u) ++c;
  }
  atomicAdd(&cnt, c);
  __syncthreads();
  if (threadIdx.x == 0) *flag = (cnt > 256u) ? 1 : 0;
}

// ---------------------------------------------------------------------------
// FP64-accumulate GEMM NT (ranking-critical layers 1,2):
// C[m,n] = relu(A[arow0+m,:]·B[n,:] + bias[n]) in f64; C fp64.
// A: f64 ws buffer (A_IS_F64) or global input per *dflag. B/bias per *dflag.
// BM=BN=64, BK=16, 256 threads, 4x4 f64 micro-tile.
// ---------------------------------------------------------------------------
template<bool A_IS_F64>
__global__ __launch_bounds__(256) void gemm_nt_f64(
    const void* __restrict__ Av, const void* __restrict__ Bv,
    const void* __restrict__ biasv, double* __restrict__ C,
    int N, int K, int arow0, const int* __restrict__ dflag)
{
  constexpr int BK = 16;
  __shared__ double As[BK][64 + 1];
  __shared__ double Bs[BK][64 + 1];
  const int f = *dflag;
  const int tid = threadIdx.x;
  const int tx = tid & 15, ty = tid >> 4;
  const int m0 = blockIdx.y * 64, n0 = blockIdx.x * 64;

  double acc[4][4];
#pragma unroll
  for (int i = 0; i < 4; ++i)
#pragma unroll
    for (int j = 0; j < 4; ++j) acc[i][j] = 0.0;

  const int row = tid >> 2;          // 0..63
  const int k4  = (tid & 3) << 2;    // 0,4,8,12

  for (int k0 = 0; k0 < K; k0 += BK) {
    if (A_IS_F64) {
      const double* Ap = (const double*)Av + (size_t)(arow0 + m0 + row) * K + (k0 + k4);
      As[k4 + 0][row] = Ap[0]; As[k4 + 1][row] = Ap[1];
      As[k4 + 2][row] = Ap[2]; As[k4 + 3][row] = Ap[3];
    } else if (f) {
      ushort4 t = *(const ushort4*)((const unsigned short*)Av + (size_t)(arow0 + m0 + row) * K + (k0 + k4));
      As[k4 + 0][row] = (double)bf2f(t.x); As[k4 + 1][row] = (double)bf2f(t.y);
      As[k4 + 2][row] = (double)bf2f(t.z); As[k4 + 3][row] = (double)bf2f(t.w);
    } else {
      float4 t = *(const float4*)((const float*)Av + (size_t)(arow0 + m0 + row) * K + (k0 + k4));
      As[k4 + 0][row] = (double)t.x; As[k4 + 1][row] = (double)t.y;
      As[k4 + 2][row] = (double)t.z; As[k4 + 3][row] = (double)t.w;
    }
    double b0 = 0.0, b1 = 0.0, b2 = 0.0, b3 = 0.0;
    if (n0 + row < N) {
      if (f) {
        ushort4 t = *(const ushort4*)((const unsigned short*)Bv + (size_t)(n0 + row) * K + (k0 + k4));
        b0 = (double)bf2f(t.x); b1 = (double)bf2f(t.y);
        b2 = (double)bf2f(t.z); b3 = (double)bf2f(t.w);
      } else {
        float4 t = *(const float4*)((const float*)Bv + (size_t)(n0 + row) * K + (k0 + k4));
        b0 = (double)t.x; b1 = (double)t.y; b2 = (double)t.z; b3 = (double)t.w;
      }
    }
    Bs[k4 + 0][row] = b0; Bs[k4 + 1][row] = b1;
    Bs[k4 + 2][row] = b2; Bs[k4 + 3][row] = b3;
    __syncthreads();
#pragma unroll
    for (int k = 0; k < BK; ++k) {
      double a[4], b[4];
#pragma unroll
      for (int i = 0; i < 4; ++i) a[i] = As[k][ty * 4 + i];
#pragma unroll
      for (int j = 0; j < 4; ++j) b[j] = Bs[k][tx * 4 + j];
#pragma unroll
      for (int i = 0; i < 4; ++i)
#pragma unroll
        for (int j = 0; j < 4; ++j)
          acc[i][j] = fma(a[i], b[j], acc[i][j]);
    }
    __syncthreads();
  }

#pragma unroll
  for (int j = 0; j < 4; ++j) {
    int n = n0 + tx * 4 + j;
    if (n < N) {
      double bv = f ? (double)bf2f(((const unsigned short*)biasv)[n])
                    : (double)((const float*)biasv)[n];
#pragma unroll
      for (int i = 0; i < 4; ++i) {
        int m = m0 + ty * 4 + i;
        C[(size_t)m * N + n] = fmax(acc[i][j] + bv, 0.0);
      }
    }
  }
}

// ---------------------------------------------------------------------------
// FP32 GEMM NT -> FLOAT32 out (layer 4; error ~1e-6 << 1.3e-3 budget).
// BM=BN=128, BK=16, 256 threads, 8x8 micro-tile. B/bias dtype per *dflag.
// ---------------------------------------------------------------------------
__global__ __launch_bounds__(256) void gemm_nt_f32(
    const float* __restrict__ A, const void* __restrict__ Bv,
    const void* __restrict__ biasv, float* __restrict__ Cout,
    int N, int K, int crow0, const int* __restrict__ dflag)
{
  constexpr int BM = 128, BK = 16;
  __shared__ float As[BK][BM + 4];
  __shared__ float Bs[BK][BM + 4];
  const int f = *dflag;
  const int tid = threadIdx.x;
  const int tx = tid & 15, ty = tid >> 4;
  const int m0 = blockIdx.y * BM, n0 = blockIdx.x * BM;

  float acc[8][8];
#pragma unroll
  for (int i = 0; i < 8; ++i)
#pragma unroll
    for (int j = 0; j < 8; ++j) acc[i][j] = 0.0f;

  for (int k0 = 0; k0 < K; k0 += BK) {
#pragma unroll
    for (int it = 0; it < 2; ++it) {
      int l = tid + it * 256;
      int row = l >> 2;
      int k4 = (l & 3) << 2;
      float4 fa = *(const float4*)(A + (size_t)(m0 + row) * K + (k0 + k4));
      As[k4 + 0][row] = fa.x; As[k4 + 1][row] = fa.y;
      As[k4 + 2][row] = fa.z; As[k4 + 3][row] = fa.w;
      float b0 = 0.f, b1 = 0.f, b2 = 0.f, b3 = 0.f;
      if (n0 + row < N) {
        if (f) {
          ushort4 t = *(const ushort4*)((const unsigned short*)Bv + (size_t)(n0 + row) * K + (k0 + k4));
          b0 = bf2f(t.x); b1 = bf2f(t.y); b2 = bf2f(t.z); b3 = bf2f(t.w);
        } else {
          float4 t = *(const float4*)((const float*)Bv + (size_t)(n0 + row) * K + (k0 + k4));
          b0 = t.x; b1 = t.y; b2 = t.z; b3 = t.w;
        }
      }
      Bs[k4 + 0][row] = b0; Bs[k4 + 1][row] = b1;
      Bs[k4 + 2][row] = b2; Bs[k4 + 3][row] = b3;
    }
    __syncthreads();
#pragma unroll
    for (int k = 0; k < BK; ++k) {
      float a[8], b[8];
      *(float4*)&a[0] = *(const float4*)&As[k][ty * 8 + 0];
      *(float4*)&a[4] = *(const float4*)&As[k][ty * 8 + 4];
      *(float4*)&b[0] = *(const float4*)&Bs[k][tx * 8 + 0];
      *(float4*)&b[4] = *(const float4*)&Bs[k][tx * 8 + 4];
#pragma unroll
      for (int i = 0; i < 8; ++i)
#pragma unroll
        for (int j = 0; j < 8; ++j)
          acc[i][j] = fmaf(a[i], b[j], acc[i][j]);
    }
    __syncthreads();
  }

#pragma unroll
  for (int j = 0; j < 8; ++j) {
    int n = n0 + tx * 8 + j;
    if (n < N) {
      float bv = f ? bf2f(((const unsigned short*)biasv)[n]) : ((const float*)biasv)[n];
#pragma unroll
      for (int i = 0; i < 8; ++i) {
        int m = crow0 + m0 + ty * 8 + i;
        Cout[(size_t)m * N + n] = fmaxf(acc[i][j] + bv, 0.0f);   // FLOAT32 out
      }
    }
  }
}

// ---------------------------------------------------------------------------
// Transpose W3 [1024][2048] -> W3T fp32 [2048][1024] for coalesced gather.
// ---------------------------------------------------------------------------
__global__ __launch_bounds__(256) void transpose_w3(
    const void* __restrict__ W3v, float* __restrict__ W3T, const int* __restrict__ dflag)
{
  __shared__ float tile[32][33];
  const int f = *dflag;
  const int tx = threadIdx.x & 31, ty = threadIdx.x >> 5;  // 32 x 8
  const int c0 = blockIdx.x * 32;
  const int r0 = blockIdx.y * 32;
#pragma unroll
  for (int i = 0; i < 32; i += 8) {
    size_t off = (size_t)(r0 + ty + i) * CODE + (c0 + tx);
    tile[ty + i][tx] = f ? bf2f(((const unsigned short*)W3v)[off])
                         : ((const float*)W3v)[off];
  }
  __syncthreads();
#pragma unroll
  for (int i = 0; i < 32; i += 8)
    W3T[(size_t)(c0 + ty + i) * INTER + (r0 + tx)] = tile[tx][ty + i];
}

// ---------------------------------------------------------------------------
// Block scans (256 threads); leading sync protects buffer reuse, trailing
// sync makes buf[] safe to read after return.
// ---------------------------------------------------------------------------
__device__ __forceinline__ unsigned scan256_incl(unsigned x, unsigned* buf, int tid) {
  __syncthreads();
  buf[tid] = x; __syncthreads();
  for (int off = 1; off < 256; off <<= 1) {
    unsigned add = (tid >= off) ? buf[tid - off] : 0u;
    __syncthreads();
    x += add; buf[tid] = x;
    __syncthreads();
  }
  return x;
}
__device__ __forceinline__ unsigned scan256_suffix(unsigned x, unsigned* buf, int tid) {
  __syncthreads();
  buf[tid] = x; __syncthreads();
  for (int off = 1; off < 256; off <<= 1) {
    unsigned add = (tid + off < 256) ? buf[tid + off] : 0u;
    __syncthreads();
    x += add; buf[tid] = x;
    __syncthreads();
  }
  return x;
}

// ---------------------------------------------------------------------------
// FP64 per-row top-64: 4-pass radix select on the double bit pattern
// (bits 62:52,51:41,40:30,29:19 -> 44-bit key; ties lowest-index-first like
// jax.lax.top_k). fp64 stripe means, top-4 stripes, compact to (f32,idx,nnz).
// One block per row; thread t owns elements [8t, 8t+8).
// ---------------------------------------------------------------------------
__global__ __launch_bounds__(256) void topk_compact_f64(
    const double* __restrict__ C, float* __restrict__ ovals,
    int* __restrict__ oidxs, int* __restrict__ onnz)
{
  __shared__ double v[CODE];            // 16 KB
  __shared__ unsigned hist[CODE];       // 8 KB
  __shared__ unsigned sbuf[256];
  __shared__ unsigned sres0, sres1, sres3;
  __shared__ int sres2;
  __shared__ double savg[NSTRIPE];
  const int tid = threadIdx.x;
  const int row = blockIdx.x;

  const double2* c2 = (const double2*)(C + (size_t)row * CODE);
#pragma unroll
  for (int i = 0; i < 4; ++i)
    ((double2*)v)[tid + 256 * i] = c2[tid + 256 * i];
  __syncthreads();

  ull u[8];
#pragma unroll
  for (int i = 0; i < 8; ++i) u[i] = __double_as_longlong(v[tid * 8 + i]);

  const int shifts[4] = {52, 41, 30, 19};
  unsigned kr = KNEUR;
  ull prefix = 0ull, pmask = 0ull;
  bool tz = false;

  for (int p = 0; p < 4; ++p) {
    const int sh = shifts[p];
    for (int i = tid; i < CODE; i += 256) hist[i] = 0u;
    __syncthreads();
#pragma unroll
    for (int i = 0; i < 8; ++i)
      if (u[i] != 0ull && (u[i] & pmask) == prefix)
        atomicAdd(&hist[(unsigned)((u[i] >> sh) & 2047ull)], 1u);
    __syncthreads();
    unsigned csum = 0u;
#pragma unroll
    for (int j = 0; j < 8; ++j) csum += hist[tid * 8 + j];
    unsigned sc = scan256_suffix(csum, sbuf, tid);
    unsigned scn = (tid < 255) ? sbuf[tid + 1] : 0u;
    if (p == 0 && tid == 0) sres2 = (sc < kr) ? 1 : 0;  // < 64 nonzero values
    if (sc >= kr && scn < kr) {
      unsigned cum = scn;
      for (int b = 7; b >= 0; --b) {
        unsigned hb = hist[tid * 8 + b];
        if (cum + hb >= kr) { sres0 = (unsigned)(tid * 8 + b); sres1 = cum; break; }
        cum += hb;
      }
    }
    __syncthreads();
    if (p == 0 && sres2) { tz = true; break; }
    kr -= sres1;
    prefix |= ((ull)sres0) << sh;
    pmask  |= 2047ull << sh;
    __syncthreads();   // selection's hist reads complete before next zeroing
  }

  const ull tkey = tz ? 0ull : (prefix >> 19);

  // exact selection: key > tkey, plus first (64 - #gt) key==tkey by index
  unsigned gt = 0u, eq = 0u;
#pragma unroll
  for (int i = 0; i < 8; ++i) {
    ull k = u[i] >> 19;
    gt += (k > tkey) ? 1u : 0u;
    eq += (k == tkey) ? 1u : 0u;
  }
  unsigned eqincl = scan256_incl(eq, sbuf, tid);
  unsigned eqbase = eqincl - eq;
  (void)scan256_incl(gt, sbuf, tid);
  unsigned total_gt = sbuf[255];
  unsigned need_eq = KNEUR - total_gt;
  unsigned er = eqbase;
#pragma unroll
  for (int i = 0; i < 8; ++i) {
    ull k = u[i] >> 19;
    bool sel = (k > tkey);
    if (k == tkey) { sel = (er < need_eq); ++er; }
    if (!sel) v[tid * 8 + i] = 0.0;
  }
  __syncthreads();

  // stripe means in fp64 (noise ~1e-16 << stripe gaps)
  if (tid < NSTRIPE) {
    const double* sv = v + tid * SDIM;
    double r0 = sv[0], r1 = sv[1], r2 = sv[2], r3 = sv[3],
           r4 = sv[4], r5 = sv[5], r6 = sv[6], r7 = sv[7];
    for (int i = 8; i < SDIM; i += 8) {
      r0 += sv[i + 0]; r1 += sv[i + 1]; r2 += sv[i + 2]; r3 += sv[i + 3];
      r4 += sv[i + 4]; r5 += sv[i + 5]; r6 += sv[i + 6]; r7 += sv[i + 7];
    }
    savg[tid] = (((r0 + r1) + (r2 + r3)) + ((r4 + r5) + (r6 + r7))) * 0.015625;
  }
  __syncthreads();
  if (tid == 0) {
    unsigned sm = 0u;
    for (int it = 0; it < KSTR; ++it) {
      double best = -1.0; int bi = 0;
      for (int s = 0; s < NSTRIPE; ++s)
        if (!((sm >> s) & 1u) && savg[s] > best) { best = savg[s]; bi = s; }
      sm |= (1u << bi);
    }
    sres3 = sm;
  }
  __syncthreads();
  const unsigned sm = sres3;

  // compact surviving nonzeros (thread's 8 elems lie in stripe tid>>3)
  const bool son = ((sm >> (tid >> 3)) & 1u) != 0u;
  double mv[8];
  unsigned act = 0u, cnt = 0u;
#pragma unroll
  for (int i = 0; i < 8; ++i) {
    mv[i] = v[tid * 8 + i];
    bool a = son && (mv[i] != 0.0);
    act |= (a ? 1u : 0u) << i;
    cnt += a ? 1u : 0u;
  }
  unsigned cincl = scan256_incl(cnt, sbuf, tid);
  unsigned pos = cincl - cnt;
  float* vrow = ovals + (size_t)row * KNEUR;
  int* irow = oidxs + (size_t)row * KNEUR;
#pragma unroll
  for (int i = 0; i < 8; ++i) {
    if ((act >> i) & 1u) {
      vrow[pos] = (float)mv[i];
      irow[pos] = tid * 8 + i;
      ++pos;
    }
  }
  if (tid == 255) onnz[row] = (int)cincl;
}

// ---------------------------------------------------------------------------
// Sparse decode (fp32): d[row,:] = relu(b3 + sum_j val_j * W3T[idx_j,:]).
// ---------------------------------------------------------------------------
__global__ __launch_bounds__(256) void sparse_decode(
    const float* __restrict__ W3T, const void* __restrict__ b3v,
    const float* __restrict__ vals, const int* __restrict__ idxs,
    const int* __restrict__ nnz, float* __restrict__ D,
    const int* __restrict__ dflag)
{
  __shared__ float sv[KNEUR];
  __shared__ int si[KNEUR];
  __shared__ int scnt;
  const int f = *dflag;
  const int tid = threadIdx.x;
  const int row = blockIdx.x;
  if (tid == 0) scnt = nnz[row];
  if (tid < KNEUR) {
    sv[tid] = vals[(size_t)row * KNEUR + tid];
    si[tid] = idxs[(size_t)row * KNEUR + tid];
  }
  __syncthreads();
  const int cnt = scnt;
  float4 acc;
  if (f) {
    const unsigned short* b3b = (const unsigned short*)b3v;
    acc.x = bf2f(b3b[4 * tid + 0]); acc.y = bf2f(b3b[4 * tid + 1]);
    acc.z = bf2f(b3b[4 * tid + 2]); acc.w = bf2f(b3b[4 * tid + 3]);
  } else {
    acc = ((const float4*)b3v)[tid];
  }
  for (int j = 0; j < cnt; ++j) {
    const float vv = sv[j];
    const float4 w = ((const float4*)(W3T + (size_t)si[j] * INTER))[tid];
    acc.x = fmaf(vv, w.x, acc.x);
    acc.y = fmaf(vv, w.y, acc.y);
    acc.z = fmaf(vv, w.z, acc.z);
    acc.w = fmaf(vv, w.w, acc.w);
  }
  acc.x = fmaxf(acc.x, 0.f); acc.y = fmaxf(acc.y, 0.f);
  acc.z = fmaxf(acc.z, 0.f); acc.w = fmaxf(acc.w, 0.f);
  ((float4*)(D + (size_t)row * INTER))[tid] = acc;
}

// ---------------------------------------------------------------------------
extern "C" void kernel_launch(void* const* d_in, const int* in_sizes, int n_in,
                              void* d_out, int out_size, void* d_ws, size_t ws_size,
                              hipStream_t stream)
{
  const void* x  = d_in[0];
  const void* W1 = d_in[1];
  const void* b1 = d_in[2];
  const void* W2 = d_in[3];
  const void* b2 = d_in[4];
  const void* W3 = d_in[5];
  const void* b3 = d_in[6];
  const void* W4 = d_in[7];
  const void* b4 = d_in[8];

  // layout: [flag 256B][W3T 8MB][h64 CH*8K (d32 overlays)][c64 CH*16K][cv][ci][cn]
  const size_t W3T_BYTES = (size_t)CODE * INTER * 4;
  int CH = BATCH;
  while (CH > 128) {
    size_t need = 256 + W3T_BYTES + (size_t)CH * (8192 + 16384 + 256 + 256 + 4);
    if (need <= ws_size) break;
    CH >>= 1;
  }
  char*   w    = (char*)d_ws;
  int*    flag = (int*)w;
  float*  W3T  = (float*)(w + 256);
  char*   p    = w + 256 + W3T_BYTES;
  double* h64  = (double*)p;                                 // CH*1024 f64
  float*  d32  = (float*)p;                                  // overlays h64 (dead by then)
  double* c64  = (double*)(p + (size_t)CH * 8192);           // CH*2048 f64
  float*  cv   = (float*)(p + (size_t)CH * 24576);           // CH*64 f32
  int*    ci   = (int*)  (p + (size_t)CH * 24576 + (size_t)CH * 256);
  int*    cn   = (int*)  (p + (size_t)CH * 24576 + (size_t)CH * 512);

  detect_dtype<<<1, 256, 0, stream>>>((const unsigned*)W1, flag);
  transpose_w3<<<dim3(CODE / 32, INTER / 32), 256, 0, stream>>>(W3, W3T, flag);

  for (int r0 = 0; r0 < BATCH; r0 += CH) {
    // h = relu(x @ W1^T + b1) in f64   [CH, 1024], K=784
    gemm_nt_f64<false><<<dim3(INTER / 64, CH / 64), 256, 0, stream>>>(
        x, W1, b1, h64, INTER, IN_DIM, r0, flag);

    // c = relu(h @ W2^T + b2) in f64   [CH, 2048], K=1024
    gemm_nt_f64<true><<<dim3(CODE / 64, CH / 64), 256, 0, stream>>>(
        h64, W2, b2, c64, CODE, INTER, 0, flag);

    // exact top-64 + stripe top-4 on f64 values -> compact sparse code
    topk_compact_f64<<<CH, 256, 0, stream>>>(c64, cv, ci, cn);

    // d = relu(c_sparse @ W3^T + b3) fp32   [CH, 1024] (overlays h64)
    sparse_decode<<<CH, 256, 0, stream>>>(W3T, b3, cv, ci, cn, d32, flag);

    // out[r0:r0+CH] = relu(d @ W4^T + b4) -> FLOAT32 [CH, 784], K=1024
    gemm_nt_f32<<<dim3((IN_DIM + 127) / 128, CH / 128), 256, 0, stream>>>(
        d32, W4, b4, (float*)d_out, IN_DIM, INTER, r0, flag);
  }
}

// Round 6
// 2705.186 us; speedup vs baseline: 1.8877x; 1.8877x over previous
//
#include <hip/hip_runtime.h>
#include <hip/hip_bf16.h>
#include <stdint.h>

typedef unsigned long long ull;
typedef double vd4 __attribute__((ext_vector_type(4)));

#define BATCH   16384
#define IN_DIM  784
#define INTER   1024
#define CODE    2048
#define NSTRIPE 32
#define SDIM    64
#define KNEUR   64
#define KSTR    4

__device__ __forceinline__ float bf2f(unsigned short u) {
  return __uint_as_float(((unsigned)u) << 16);
}

// ---------------------------------------------------------------------------
// Input dtype detector (insurance): flag=1 => inputs are bf16.
// ---------------------------------------------------------------------------
__global__ void detect_dtype(const unsigned* __restrict__ w1raw, int* __restrict__ flag) {
  __shared__ unsigned cnt;
  if (threadIdx.x == 0) cnt = 0u;
  __syncthreads();
  unsigned c = 0;
  for (int i = threadIdx.x; i < 512; i += 256) {
    unsigned e = (w1raw[i] >> 7) & 0xFFu;
    if (e >= 100u && e <= 126u) ++c;
  }
  atomicAdd(&cnt, c);
  __syncthreads();
  if (threadIdx.x == 0) *flag = (cnt > 256u) ? 1 : 0;
}

// ---------------------------------------------------------------------------
// FP64 MFMA GEMM NT (ranking-critical layers 1,2):
// C[m,n] = relu(A[arow0+m,:]·B[n,:] + bias[n]) in f64, via v_mfma_f64_16x16x4.
// 64x64 tile per block, 4 waves, each wave a 32x32 (2x2 of 16x16 MFMA tiles).
// LDS [k][m] layout, LD=64: fragment reads hit all 32 banks once per lane
// quarter -> zero conflicts (vs 4.7e8 conflict cycles in the VALU version).
// N, K must be multiples of 64/16 (true for 1024/2048 x 784/1024).
// ---------------------------------------------------------------------------
template<bool A_IS_F64>
__global__ __launch_bounds__(256) void gemm_nt_f64_mfma(
    const void* __restrict__ Av, const void* __restrict__ Bv,
    const void* __restrict__ biasv, double* __restrict__ C,
    int N, int K, int arow0, const int* __restrict__ dflag)
{
  __shared__ double As[16][64];   // [k][m]
  __shared__ double Bs[16][64];   // [k][n]
  const int f = *dflag;
  const int tid  = threadIdx.x;
  const int lane = tid & 63;
  const int wave = tid >> 6;            // 0..3
  const int wr = wave >> 1, wc = wave & 1;
  const int m0 = blockIdx.y * 64, n0 = blockIdx.x * 64;

  const int srow = tid >> 2;            // 0..63 staging row
  const int sk4  = (tid & 3) << 2;      // 0,4,8,12

  vd4 acc[2][2];
#pragma unroll
  for (int i = 0; i < 2; ++i)
#pragma unroll
    for (int j = 0; j < 2; ++j)
#pragma unroll
      for (int r = 0; r < 4; ++r) acc[i][j][r] = 0.0;

  const int lm = lane & 15;             // m/n within 16-tile
  const int lq = lane >> 4;             // k within 4-chunk

  for (int k0 = 0; k0 < K; k0 += 16) {
    // ---- stage A tile (64 rows x 16 k) ----
    if (A_IS_F64) {
      const double* Ap = (const double*)Av + (size_t)(arow0 + m0 + srow) * K + (k0 + sk4);
      As[sk4 + 0][srow] = Ap[0]; As[sk4 + 1][srow] = Ap[1];
      As[sk4 + 2][srow] = Ap[2]; As[sk4 + 3][srow] = Ap[3];
    } else if (f) {
      ushort4 t = *(const ushort4*)((const unsigned short*)Av +
                   (size_t)(arow0 + m0 + srow) * K + (k0 + sk4));
      As[sk4 + 0][srow] = (double)bf2f(t.x); As[sk4 + 1][srow] = (double)bf2f(t.y);
      As[sk4 + 2][srow] = (double)bf2f(t.z); As[sk4 + 3][srow] = (double)bf2f(t.w);
    } else {
      float4 t = *(const float4*)((const float*)Av +
                  (size_t)(arow0 + m0 + srow) * K + (k0 + sk4));
      As[sk4 + 0][srow] = (double)t.x; As[sk4 + 1][srow] = (double)t.y;
      As[sk4 + 2][srow] = (double)t.z; As[sk4 + 3][srow] = (double)t.w;
    }
    // ---- stage B tile (64 rows x 16 k) ----
    if (f) {
      ushort4 t = *(const ushort4*)((const unsigned short*)Bv +
                   (size_t)(n0 + srow) * K + (k0 + sk4));
      Bs[sk4 + 0][srow] = (double)bf2f(t.x); Bs[sk4 + 1][srow] = (double)bf2f(t.y);
      Bs[sk4 + 2][srow] = (double)bf2f(t.z); Bs[sk4 + 3][srow] = (double)bf2f(t.w);
    } else {
      float4 t = *(const float4*)((const float*)Bv +
                  (size_t)(n0 + srow) * K + (k0 + sk4));
      Bs[sk4 + 0][srow] = (double)t.x; Bs[sk4 + 1][srow] = (double)t.y;
      Bs[sk4 + 2][srow] = (double)t.z; Bs[sk4 + 3][srow] = (double)t.w;
    }
    __syncthreads();

#pragma unroll
    for (int ks = 0; ks < 4; ++ks) {
      const int kk = ks * 4 + lq;
      double a0 = As[kk][wr * 32 + lm];
      double a1 = As[kk][wr * 32 + 16 + lm];
      double b0 = Bs[kk][wc * 32 + lm];
      double b1 = Bs[kk][wc * 32 + 16 + lm];
      acc[0][0] = __builtin_amdgcn_mfma_f64_16x16x4f64(a0, b0, acc[0][0], 0, 0, 0);
      acc[0][1] = __builtin_amdgcn_mfma_f64_16x16x4f64(a0, b1, acc[0][1], 0, 0, 0);
      acc[1][0] = __builtin_amdgcn_mfma_f64_16x16x4f64(a1, b0, acc[1][0], 0, 0, 0);
      acc[1][1] = __builtin_amdgcn_mfma_f64_16x16x4f64(a1, b1, acc[1][1], 0, 0, 0);
    }
    __syncthreads();
  }

  // ---- epilogue: D col = lane&15, row = (lane>>4)*4 + reg ----
#pragma unroll
  for (int tc = 0; tc < 2; ++tc) {
    const int col = n0 + wc * 32 + tc * 16 + lm;
    const double bv = f ? (double)bf2f(((const unsigned short*)biasv)[col])
                        : (double)((const float*)biasv)[col];
#pragma unroll
    for (int tr = 0; tr < 2; ++tr) {
#pragma unroll
      for (int r = 0; r < 4; ++r) {
        const int row = m0 + wr * 32 + tr * 16 + lq * 4 + r;
        C[(size_t)row * N + col] = fmax(acc[tr][tc][r] + bv, 0.0);
      }
    }
  }
}

// ---------------------------------------------------------------------------
// FP32 GEMM NT -> FLOAT32 out (layer 4).
// BM=BN=128, BK=16, 256 threads, 8x8 micro-tile. B/bias dtype per *dflag.
// ---------------------------------------------------------------------------
__global__ __launch_bounds__(256) void gemm_nt_f32(
    const float* __restrict__ A, const void* __restrict__ Bv,
    const void* __restrict__ biasv, float* __restrict__ Cout,
    int N, int K, int crow0, const int* __restrict__ dflag)
{
  constexpr int BM = 128, BK = 16;
  __shared__ float As[BK][BM + 4];
  __shared__ float Bs[BK][BM + 4];
  const int f = *dflag;
  const int tid = threadIdx.x;
  const int tx = tid & 15, ty = tid >> 4;
  const int m0 = blockIdx.y * BM, n0 = blockIdx.x * BM;

  float acc[8][8];
#pragma unroll
  for (int i = 0; i < 8; ++i)
#pragma unroll
    for (int j = 0; j < 8; ++j) acc[i][j] = 0.0f;

  for (int k0 = 0; k0 < K; k0 += BK) {
#pragma unroll
    for (int it = 0; it < 2; ++it) {
      int l = tid + it * 256;
      int row = l >> 2;
      int k4 = (l & 3) << 2;
      float4 fa = *(const float4*)(A + (size_t)(m0 + row) * K + (k0 + k4));
      As[k4 + 0][row] = fa.x; As[k4 + 1][row] = fa.y;
      As[k4 + 2][row] = fa.z; As[k4 + 3][row] = fa.w;
      float b0 = 0.f, b1 = 0.f, b2 = 0.f, b3 = 0.f;
      if (n0 + row < N) {
        if (f) {
          ushort4 t = *(const ushort4*)((const unsigned short*)Bv + (size_t)(n0 + row) * K + (k0 + k4));
          b0 = bf2f(t.x); b1 = bf2f(t.y); b2 = bf2f(t.z); b3 = bf2f(t.w);
        } else {
          float4 t = *(const float4*)((const float*)Bv + (size_t)(n0 + row) * K + (k0 + k4));
          b0 = t.x; b1 = t.y; b2 = t.z; b3 = t.w;
        }
      }
      Bs[k4 + 0][row] = b0; Bs[k4 + 1][row] = b1;
      Bs[k4 + 2][row] = b2; Bs[k4 + 3][row] = b3;
    }
    __syncthreads();
#pragma unroll
    for (int k = 0; k < BK; ++k) {
      float a[8], b[8];
      *(float4*)&a[0] = *(const float4*)&As[k][ty * 8 + 0];
      *(float4*)&a[4] = *(const float4*)&As[k][ty * 8 + 4];
      *(float4*)&b[0] = *(const float4*)&Bs[k][tx * 8 + 0];
      *(float4*)&b[4] = *(const float4*)&Bs[k][tx * 8 + 4];
#pragma unroll
      for (int i = 0; i < 8; ++i)
#pragma unroll
        for (int j = 0; j < 8; ++j)
          acc[i][j] = fmaf(a[i], b[j], acc[i][j]);
    }
    __syncthreads();
  }

#pragma unroll
  for (int j = 0; j < 8; ++j) {
    int n = n0 + tx * 8 + j;
    if (n < N) {
      float bv = f ? bf2f(((const unsigned short*)biasv)[n]) : ((const float*)biasv)[n];
#pragma unroll
      for (int i = 0; i < 8; ++i) {
        int m = crow0 + m0 + ty * 8 + i;
        Cout[(size_t)m * N + n] = fmaxf(acc[i][j] + bv, 0.0f);
      }
    }
  }
}

// ---------------------------------------------------------------------------
// Transpose W3 [1024][2048] -> W3T fp32 [2048][1024] for coalesced gather.
// ---------------------------------------------------------------------------
__global__ __launch_bounds__(256) void transpose_w3(
    const void* __restrict__ W3v, float* __restrict__ W3T, const int* __restrict__ dflag)
{
  __shared__ float tile[32][33];
  const int f = *dflag;
  const int tx = threadIdx.x & 31, ty = threadIdx.x >> 5;  // 32 x 8
  const int c0 = blockIdx.x * 32;
  const int r0 = blockIdx.y * 32;
#pragma unroll
  for (int i = 0; i < 32; i += 8) {
    size_t off = (size_t)(r0 + ty + i) * CODE + (c0 + tx);
    tile[ty + i][tx] = f ? bf2f(((const unsigned short*)W3v)[off])
                         : ((const float*)W3v)[off];
  }
  __syncthreads();
#pragma unroll
  for (int i = 0; i < 32; i += 8)
    W3T[(size_t)(c0 + ty + i) * INTER + (r0 + tx)] = tile[tx][ty + i];
}

// ---------------------------------------------------------------------------
// Block scans (256 threads).
// ---------------------------------------------------------------------------
__device__ __forceinline__ unsigned scan256_incl(unsigned x, unsigned* buf, int tid) {
  __syncthreads();
  buf[tid] = x; __syncthreads();
  for (int off = 1; off < 256; off <<= 1) {
    unsigned add = (tid >= off) ? buf[tid - off] : 0u;
    __syncthreads();
    x += add; buf[tid] = x;
    __syncthreads();
  }
  return x;
}
__device__ __forceinline__ unsigned scan256_suffix(unsigned x, unsigned* buf, int tid) {
  __syncthreads();
  buf[tid] = x; __syncthreads();
  for (int off = 1; off < 256; off <<= 1) {
    unsigned add = (tid + off < 256) ? buf[tid + off] : 0u;
    __syncthreads();
    x += add; buf[tid] = x;
    __syncthreads();
  }
  return x;
}

// ---------------------------------------------------------------------------
// FP64 per-row top-64 radix select (44-bit key, ties lowest-index-first),
// fp64 stripe means, top-4 stripes, compaction to (f32 val, idx, nnz).
// ---------------------------------------------------------------------------
__global__ __launch_bounds__(256) void topk_compact_f64(
    const double* __restrict__ C, float* __restrict__ ovals,
    int* __restrict__ oidxs, int* __restrict__ onnz)
{
  __shared__ double v[CODE];            // 16 KB
  __shared__ unsigned hist[CODE];       // 8 KB
  __shared__ unsigned sbuf[256];
  __shared__ unsigned sres0, sres1, sres3;
  __shared__ int sres2;
  __shared__ double savg[NSTRIPE];
  const int tid = threadIdx.x;
  const int row = blockIdx.x;

  const double2* c2 = (const double2*)(C + (size_t)row * CODE);
#pragma unroll
  for (int i = 0; i < 4; ++i)
    ((double2*)v)[tid + 256 * i] = c2[tid + 256 * i];
  __syncthreads();

  ull u[8];
#pragma unroll
  for (int i = 0; i < 8; ++i) u[i] = __double_as_longlong(v[tid * 8 + i]);

  const int shifts[4] = {52, 41, 30, 19};
  unsigned kr = KNEUR;
  ull prefix = 0ull, pmask = 0ull;
  bool tz = false;

  for (int p = 0; p < 4; ++p) {
    const int sh = shifts[p];
    for (int i = tid; i < CODE; i += 256) hist[i] = 0u;
    __syncthreads();
#pragma unroll
    for (int i = 0; i < 8; ++i)
      if (u[i] != 0ull && (u[i] & pmask) == prefix)
        atomicAdd(&hist[(unsigned)((u[i] >> sh) & 2047ull)], 1u);
    __syncthreads();
    unsigned csum = 0u;
#pragma unroll
    for (int j = 0; j < 8; ++j) csum += hist[tid * 8 + j];
    unsigned sc = scan256_suffix(csum, sbuf, tid);
    unsigned scn = (tid < 255) ? sbuf[tid + 1] : 0u;
    if (p == 0 && tid == 0) sres2 = (sc < kr) ? 1 : 0;
    if (sc >= kr && scn < kr) {
      unsigned cum = scn;
      for (int b = 7; b >= 0; --b) {
        unsigned hb = hist[tid * 8 + b];
        if (cum + hb >= kr) { sres0 = (unsigned)(tid * 8 + b); sres1 = cum; break; }
        cum += hb;
      }
    }
    __syncthreads();
    if (p == 0 && sres2) { tz = true; break; }
    kr -= sres1;
    prefix |= ((ull)sres0) << sh;
    pmask  |= 2047ull << sh;
    __syncthreads();
  }

  const ull tkey = tz ? 0ull : (prefix >> 19);

  unsigned gt = 0u, eq = 0u;
#pragma unroll
  for (int i = 0; i < 8; ++i) {
    ull k = u[i] >> 19;
    gt += (k > tkey) ? 1u : 0u;
    eq += (k == tkey) ? 1u : 0u;
  }
  unsigned eqincl = scan256_incl(eq, sbuf, tid);
  unsigned eqbase = eqincl - eq;
  (void)scan256_incl(gt, sbuf, tid);
  unsigned total_gt = sbuf[255];
  unsigned need_eq = KNEUR - total_gt;
  unsigned er = eqbase;
#pragma unroll
  for (int i = 0; i < 8; ++i) {
    ull k = u[i] >> 19;
    bool sel = (k > tkey);
    if (k == tkey) { sel = (er < need_eq); ++er; }
    if (!sel) v[tid * 8 + i] = 0.0;
  }
  __syncthreads();

  if (tid < NSTRIPE) {
    const double* sv = v + tid * SDIM;
    double r0 = sv[0], r1 = sv[1], r2 = sv[2], r3 = sv[3],
           r4 = sv[4], r5 = sv[5], r6 = sv[6], r7 = sv[7];
    for (int i = 8; i < SDIM; i += 8) {
      r0 += sv[i + 0]; r1 += sv[i + 1]; r2 += sv[i + 2]; r3 += sv[i + 3];
      r4 += sv[i + 4]; r5 += sv[i + 5]; r6 += sv[i + 6]; r7 += sv[i + 7];
    }
    savg[tid] = (((r0 + r1) + (r2 + r3)) + ((r4 + r5) + (r6 + r7))) * 0.015625;
  }
  __syncthreads();
  if (tid == 0) {
    unsigned sm = 0u;
    for (int it = 0; it < KSTR; ++it) {
      double best = -1.0; int bi = 0;
      for (int s = 0; s < NSTRIPE; ++s)
        if (!((sm >> s) & 1u) && savg[s] > best) { best = savg[s]; bi = s; }
      sm |= (1u << bi);
    }
    sres3 = sm;
  }
  __syncthreads();
  const unsigned sm = sres3;

  const bool son = ((sm >> (tid >> 3)) & 1u) != 0u;
  double mv[8];
  unsigned act = 0u, cnt = 0u;
#pragma unroll
  for (int i = 0; i < 8; ++i) {
    mv[i] = v[tid * 8 + i];
    bool a = son && (mv[i] != 0.0);
    act |= (a ? 1u : 0u) << i;
    cnt += a ? 1u : 0u;
  }
  unsigned cincl = scan256_incl(cnt, sbuf, tid);
  unsigned pos = cincl - cnt;
  float* vrow = ovals + (size_t)row * KNEUR;
  int* irow = oidxs + (size_t)row * KNEUR;
#pragma unroll
  for (int i = 0; i < 8; ++i) {
    if ((act >> i) & 1u) {
      vrow[pos] = (float)mv[i];
      irow[pos] = tid * 8 + i;
      ++pos;
    }
  }
  if (tid == 255) onnz[row] = (int)cincl;
}

// ---------------------------------------------------------------------------
// Sparse decode (fp32): d[row,:] = relu(b3 + sum_j val_j * W3T[idx_j,:]).
// ---------------------------------------------------------------------------
__global__ __launch_bounds__(256) void sparse_decode(
    const float* __restrict__ W3T, const void* __restrict__ b3v,
    const float* __restrict__ vals, const int* __restrict__ idxs,
    const int* __restrict__ nnz, float* __restrict__ D,
    const int* __restrict__ dflag)
{
  __shared__ float sv[KNEUR];
  __shared__ int si[KNEUR];
  __shared__ int scnt;
  const int f = *dflag;
  const int tid = threadIdx.x;
  const int row = blockIdx.x;
  if (tid == 0) scnt = nnz[row];
  if (tid < KNEUR) {
    sv[tid] = vals[(size_t)row * KNEUR + tid];
    si[tid] = idxs[(size_t)row * KNEUR + tid];
  }
  __syncthreads();
  const int cnt = scnt;
  float4 acc;
  if (f) {
    const unsigned short* b3b = (const unsigned short*)b3v;
    acc.x = bf2f(b3b[4 * tid + 0]); acc.y = bf2f(b3b[4 * tid + 1]);
    acc.z = bf2f(b3b[4 * tid + 2]); acc.w = bf2f(b3b[4 * tid + 3]);
  } else {
    acc = ((const float4*)b3v)[tid];
  }
  for (int j = 0; j < cnt; ++j) {
    const float vv = sv[j];
    const float4 w = ((const float4*)(W3T + (size_t)si[j] * INTER))[tid];
    acc.x = fmaf(vv, w.x, acc.x);
    acc.y = fmaf(vv, w.y, acc.y);
    acc.z = fmaf(vv, w.z, acc.z);
    acc.w = fmaf(vv, w.w, acc.w);
  }
  acc.x = fmaxf(acc.x, 0.f); acc.y = fmaxf(acc.y, 0.f);
  acc.z = fmaxf(acc.z, 0.f); acc.w = fmaxf(acc.w, 0.f);
  ((float4*)(D + (size_t)row * INTER))[tid] = acc;
}

// ---------------------------------------------------------------------------
extern "C" void kernel_launch(void* const* d_in, const int* in_sizes, int n_in,
                              void* d_out, int out_size, void* d_ws, size_t ws_size,
                              hipStream_t stream)
{
  const void* x  = d_in[0];
  const void* W1 = d_in[1];
  const void* b1 = d_in[2];
  const void* W2 = d_in[3];
  const void* b2 = d_in[4];
  const void* W3 = d_in[5];
  const void* b3 = d_in[6];
  const void* W4 = d_in[7];
  const void* b4 = d_in[8];

  // layout: [flag 256B][W3T 8MB][h64 CH*8K (d32 overlays)][c64 CH*16K][cv][ci][cn]
  const size_t W3T_BYTES = (size_t)CODE * INTER * 4;
  int CH = BATCH;
  while (CH > 128) {
    size_t need = 256 + W3T_BYTES + (size_t)CH * (8192 + 16384 + 256 + 256 + 4);
    if (need <= ws_size) break;
    CH >>= 1;
  }
  char*   w    = (char*)d_ws;
  int*    flag = (int*)w;
  float*  W3T  = (float*)(w + 256);
  char*   p    = w + 256 + W3T_BYTES;
  double* h64  = (double*)p;                                 // CH*1024 f64
  float*  d32  = (float*)p;                                  // overlays h64 (dead by then)
  double* c64  = (double*)(p + (size_t)CH * 8192);           // CH*2048 f64
  float*  cv   = (float*)(p + (size_t)CH * 24576);           // CH*64 f32
  int*    ci   = (int*)  (p + (size_t)CH * 24576 + (size_t)CH * 256);
  int*    cn   = (int*)  (p + (size_t)CH * 24576 + (size_t)CH * 512);

  detect_dtype<<<1, 256, 0, stream>>>((const unsigned*)W1, flag);
  transpose_w3<<<dim3(CODE / 32, INTER / 32), 256, 0, stream>>>(W3, W3T, flag);

  for (int r0 = 0; r0 < BATCH; r0 += CH) {
    // h = relu(x @ W1^T + b1) in f64   [CH, 1024], K=784  (MFMA f64)
    gemm_nt_f64_mfma<false><<<dim3(INTER / 64, CH / 64), 256, 0, stream>>>(
        x, W1, b1, h64, INTER, IN_DIM, r0, flag);

    // c = relu(h @ W2^T + b2) in f64   [CH, 2048], K=1024  (MFMA f64)
    gemm_nt_f64_mfma<true><<<dim3(CODE / 64, CH / 64), 256, 0, stream>>>(
        h64, W2, b2, c64, CODE, INTER, 0, flag);

    // exact top-64 + stripe top-4 on f64 values -> compact sparse code
    topk_compact_f64<<<CH, 256, 0, stream>>>(c64, cv, ci, cn);

    // d = relu(c_sparse @ W3^T + b3) fp32   [CH, 1024] (overlays h64)
    sparse_decode<<<CH, 256, 0, stream>>>(W3T, b3, cv, ci, cn, d32, flag);

    // out[r0:r0+CH] = relu(d @ W4^T + b4) -> FLOAT32 [CH, 784], K=1024
    gemm_nt_f32<<<dim3((IN_DIM + 127) / 128, CH / 128), 256, 0, stream>>>(
        d32, W4, b4, (float*)d_out, IN_DIM, INTER, r0, flag);
  }
}